// Round 6
// baseline (796.977 us; speedup 1.0000x reference)
//
#include <hip/hip_runtime.h>

// CharRNN fused: B=256, L=1024, V=40, H=128. One block/CU, 256 thr = 4 waves.
// R6 (from R3 base): wave w owns k-quarter [32w,32w+32); h in registers,
// broadcast via v_readlane. Changes vs R3:
//  - partials transposed to part[j][slot], slot=(w+j)&3 swizzle: writes
//    conflict-free, reduce = ONE ds_read_b128 (sum is order-invariant).
//  - logit loop moved AFTER the barrier: computes row t-1 from the old hreg
//    while the b128 reduce read is in flight (fills ~130cy LDS latency).
//  - lanes 32-63 mirror lanes 0-31 (lane&31) -> no exec-mask churn anywhere
//    in the steady-state loop; all LDS accesses in-bounds by construction.
//  - x[] via wave-uniform s_load prefetch (no xbuf), lpart padded to 64 cols
//    so its write needs no guard.

#define BB 256
#define LL 1024
#define VV 40
#define HH 128
#define WIN 32

__device__ __forceinline__ float fast_tanh(float x) {
    // tanh(x) = 1 - 2/(exp(2x)+1); overflow -> inf -> rcp -> 0 -> +1 (correct)
    float e = __expf(2.0f * x);
    float r = __builtin_amdgcn_rcpf(e + 1.0f);
    return 1.0f - 2.0f * r;
}

__device__ __forceinline__ float bcast(float v, int k) {
    return __int_as_float(__builtin_amdgcn_readlane(__float_as_int(v), k));
}

__global__ __launch_bounds__(256, 1) void rnn_fused(
    const int*   __restrict__ x,       // [B,L]
    const float* __restrict__ hidden,  // [B,H]
    const float* __restrict__ emb,     // [V,H]
    const float* __restrict__ Wh,      // [H,H]
    const float* __restrict__ Wo,      // [V,H]
    const float* __restrict__ b_h,     // [H]
    const float* __restrict__ b_y,     // [V]
    float*       __restrict__ out)     // [B*L*V logits][B*H final_hidden]
{
    __shared__ float emb_s[VV * HH];      // 20 KB (b_h folded in)
    __shared__ float part_f[2 * HH * 4];  //  4 KB  [p][j][slot], slot swizzled
    __shared__ float lpart[WIN][4][64];   // 32 KB  logit partials (pad 40->64)
    __shared__ float bys[VV];
    // ~56.4 KB static LDS

    const int tid  = threadIdx.x;
    const int b    = blockIdx.x;
    const int w    = tid >> 6;           // wave 0..3
    const int lane = tid & 63;
    const int kq   = w << 5;             // wave's k-quarter base
    const int l32  = lane & 31;          // lanes 32-63 mirror 0-31

    // ---- stage embedding(+b_h), b_y ----
    for (int i = tid; i < VV * HH; i += 256)
        emb_s[i] = emb[i] + b_h[i & (HH - 1)];
    if (tid < VV) bys[tid] = b_y[tid];

    // ---- weights into registers ----
    // wreg0[k]=Wh[lane][kq+k], wreg1[k]=Wh[lane+64][kq+k], woreg[k]=Wo[min(lane,39)][kq+k]
    float wreg0[32], wreg1[32], woreg[32];
    {
        const float4* p0 = (const float4*)(Wh + (size_t)lane * HH + kq);
        const float4* p1 = (const float4*)(Wh + (size_t)(lane + 64) * HH + kq);
        int vrow = (lane < VV) ? lane : 0;
        const float4* p2 = (const float4*)(Wo + (size_t)vrow * HH + kq);
        #pragma unroll
        for (int i = 0; i < 8; i++) {
            float4 a = p0[i], c = p1[i], d = p2[i];
            wreg0[4*i+0] = a.x; wreg0[4*i+1] = a.y; wreg0[4*i+2] = a.z; wreg0[4*i+3] = a.w;
            wreg1[4*i+0] = c.x; wreg1[4*i+1] = c.y; wreg1[4*i+2] = c.z; wreg1[4*i+3] = c.w;
            woreg[4*i+0] = d.x; woreg[4*i+1] = d.y; woreg[4*i+2] = d.z; woreg[4*i+3] = d.w;
        }
    }
    // hreg: lanes 0-31 hold h[kq+lane]; lanes 32-63 mirror (kept valid all loop)
    float hreg = hidden[(size_t)b * HH + kq + l32];
    __syncthreads();

    // precomputed addressing
    const int slot   = (w + lane) & 3;       // same for j=lane and j=lane+64
    const int wbase  = (lane << 2) + slot;   // part word index, j=lane, p=0
    const int eoff   = kq + l32;
    const size_t outb = (size_t)b * LL * VV;
    const int* xrow  = x + (size_t)b * LL;

    int idx_cur = xrow[0];                   // uniform -> s_load
    int p = 0;

    for (int t = 0; t < LL; ++t) {
        // e_t (issued early; k-loop hides LDS latency). All lanes in-bounds.
        float e_cur = emb_s[idx_cur * HH + eoff];
        int tn = t + 1; if (tn > LL - 1) tn = LL - 1;
        int idx_next = xrow[tn];             // uniform prefetch

        // ---- broadcast k-loop over my k-quarter (h-dot only) ----
        float acc0 = 0.f, acc1 = 0.f;
        #pragma unroll
        for (int k = 0; k < 32; ++k) {
            float s = bcast(hreg, k);        // h_{t-1}[kq+k]
            acc0 = fmaf(s, wreg0[k], acc0);  // j = lane
            acc1 = fmaf(s, wreg1[k], acc1);  // j = lane+64
        }
        part_f[(p << 9) + wbase]       = acc0;   // swizzled slot: conflict-free
        part_f[(p << 9) + wbase + 256] = acc1;
        __syncthreads();

        // issue the reduce read NOW (latency hidden by burst/logit below)
        float4 pr = ((const float4*)part_f)[(p << 7) + kq + l32];

        // ---- burst: rows [t-33, t-1) every 32 steps ----
        if (t >= 33 && (t & (WIN - 1)) == 1) {
            const int rb = t - 33;
            #pragma unroll
            for (int q = 0; q < 5; ++q) {
                int o  = tid + 256 * q;      // 0..1279 == WIN*VV-1
                int tp = o / VV;
                int v  = o - VV * tp;
                int sl = (rb + tp) & (WIN - 1);
                float sm = bys[v] + lpart[sl][0][v] + lpart[sl][1][v]
                                  + lpart[sl][2][v] + lpart[sl][3][v];
                out[outb + (size_t)(rb + tp) * VV + v] = sm;
            }
            __syncthreads();   // slots must be fully read before overwrite below
        }

        // ---- logits for row t-1 from hreg = h_{t-1} (fills pr latency) ----
        float lacc = 0.f;
        #pragma unroll
        for (int k = 0; k < 32; ++k)
            lacc = fmaf(bcast(hreg, k), woreg[k], lacc);
        lpart[(t - 1) & (WIN - 1)][w][lane] = lacc;  // lanes>=40 write pad

        // ---- reduce + tanh (all lanes; 32-63 mirror 0-31) ----
        float vsum = (pr.x + pr.y) + (pr.z + pr.w) + e_cur;
        hreg = fast_tanh(vsum);
        idx_cur = idx_next;
        p ^= 1;
    }

    // ---- epilogue: row 1023 logits, final burst rows 992..1023, final h ----
    {
        float lacc = 0.f;
        #pragma unroll
        for (int k = 0; k < 32; ++k)
            lacc = fmaf(bcast(hreg, k), woreg[k], lacc);
        lpart[31][w][lane] = lacc;           // row 1023 -> slot 31
        __syncthreads();
        #pragma unroll
        for (int q = 0; q < 5; ++q) {
            int o  = tid + 256 * q;
            int tp = o / VV;                 // rows 992..1023 sit in slots 0..31
            int v  = o - VV * tp;
            float sm = bys[v] + lpart[tp][0][v] + lpart[tp][1][v]
                              + lpart[tp][2][v] + lpart[tp][3][v];
            out[outb + (size_t)(992 + tp) * VV + v] = sm;
        }
        if (lane < 32)
            out[(size_t)BB * LL * VV + (size_t)b * HH + kq + lane] = hreg;
    }
}

extern "C" void kernel_launch(void* const* d_in, const int* in_sizes, int n_in,
                              void* d_out, int out_size, void* d_ws, size_t ws_size,
                              hipStream_t stream) {
    const int*   x      = (const int*)  d_in[0];
    const float* hidden = (const float*)d_in[1];
    const float* emb    = (const float*)d_in[2];
    const float* Wh     = (const float*)d_in[3];
    const float* Wo     = (const float*)d_in[4];
    const float* bh     = (const float*)d_in[5];
    const float* by     = (const float*)d_in[6];
    float*       out    = (float*)      d_out;

    rnn_fused<<<dim3(BB), dim3(256), 0, stream>>>(x, hidden, emb, Wh, Wo, bh, by, out);
}

// Round 7
// 669.887 us; speedup vs baseline: 1.1897x; 1.1897x over previous
//
#include <hip/hip_runtime.h>
#include <stdint.h>

// CharRNN via MFMA: B=256, L=1024, V=40, H=128.
// 16 blocks x 16 batch rows; per step: h_new[16,128] = tanh([h | onehot(x) | 1]
//   @ [Wh | emb^T(+residual) | b_h]^T) as one 16x16x(7*32) bf16 MFMA chain.
// K-augmentation: p = k-128: p<40 -> bf16(emb[p][j]); p==40 -> b_h[j] (A has
// constant 1); p in 41..48 -> bf16 residual of emb[32..39]; p in 64..95 ->
// bf16 residual of emb[0..31]. A-side onehot frags come from a small LDS
// table indexed by x[m][t] -> emb enters at ~fp32 accuracy.
// Logits[t-1] = afrag(h_t) @ Wo^T piggyback on the same A-frags (waves 0-2).
// One barrier/step; h ping-pongs as bf16 in LDS (pad 136 to spread banks).
// Final hidden stored fp32 straight from the last tanh registers.

#define BB 256
#define LL 1024
#define VV 40
#define HH 128
#define MROWS 16
#define HPAD 136   // bf16 elements per h row (136*2B=272B = 17*16B -> quads spread)

typedef float f32x4 __attribute__((ext_vector_type(4)));
typedef short s16x8 __attribute__((ext_vector_type(8)));

union S8 { s16x8 v; unsigned short u[8]; };

__device__ __forceinline__ unsigned short f2bf(float f) {
    unsigned int u = __float_as_uint(f);
    return (unsigned short)((u + 0x7FFFu + ((u >> 16) & 1u)) >> 16);  // RNE
}
__device__ __forceinline__ float bf2f(unsigned short h) {
    return __uint_as_float(((unsigned int)h) << 16);
}
__device__ __forceinline__ float fast_tanh(float x) {
    // tanh(x) = 1 - 2/(exp(2x)+1); overflow -> inf -> rcp -> 0 -> +1 (correct)
    float e = __expf(2.0f * x);
    float r = __builtin_amdgcn_rcpf(e + 1.0f);
    return 1.0f - 2.0f * r;
}
__device__ __forceinline__ f32x4 MFMA(s16x8 a, s16x8 b, f32x4 c) {
    return __builtin_amdgcn_mfma_f32_16x16x32_bf16(a, b, c, 0, 0, 0);
}

__global__ __launch_bounds__(256, 1) void rnn_mfma(
    const int*   __restrict__ x,       // [B,L]
    const float* __restrict__ hidden,  // [B,H]
    const float* __restrict__ emb,     // [V,H]
    const float* __restrict__ Wh,      // [H,H]
    const float* __restrict__ Wo,      // [V,H]
    const float* __restrict__ b_h,     // [H]
    const float* __restrict__ b_y,     // [V]
    float*       __restrict__ out)     // [B*L*V logits][B*H final_hidden]
{
    __shared__ unsigned char xs[MROWS * LL];                        // 16 KB
    __shared__ alignas(16) unsigned short htile[2][MROWS * HPAD];   // 8.5 KB
    __shared__ alignas(16) unsigned short ohtab[VV * 96];           // 7.5 KB

    const int tid  = threadIdx.x;
    const int w    = tid >> 6;       // wave 0..3
    const int lane = tid & 63;
    const int quad = lane >> 4;
    const int l16  = lane & 15;
    const int b0   = blockIdx.x * MROWS;

    // ---- stage x as bytes [m][t] ----
    for (int i = tid; i < MROWS * LL; i += 256) {
        int m = i >> 10, t = i & (LL - 1);
        xs[i] = (unsigned char)x[(size_t)(b0 + m) * LL + t];
    }
    // ---- onehot A-table: row v (96 bf16) covers k-aug positions p=0..95 ----
    for (int i = tid; i < VV * 96; i += 256) ohtab[i] = 0;
    __syncthreads();
    if (tid < VV) {
        const unsigned short one = 0x3F80;                  // bf16(1.0)
        ohtab[tid * 96 + tid] = one;                        // main onehot
        ohtab[tid * 96 + 40]  = one;                        // bias column
        int pr = (tid < 32) ? (64 + tid) : (41 + (tid - 32));
        ohtab[tid * 96 + pr]  = one;                        // residual onehot
    }
    // ---- h_init -> htile[0] (bf16) ----
    for (int i = tid; i < MROWS * HH; i += 256) {
        int m = i >> 7, k = i & (HH - 1);
        htile[0][m * HPAD + k] = f2bf(hidden[(size_t)(b0 + m) * HH + k]);
    }

    // ---- B-frags in registers (MFMA reads them from AGPR for free) ----
    // wh[nt][f]: n-tile j = 32w+16nt+l16; f<4: Wh[j][k]; f>=4: aug columns.
    s16x8 wh[2][7];
    #pragma unroll
    for (int nt = 0; nt < 2; ++nt) {
        int j = 32 * w + 16 * nt + l16;
        #pragma unroll
        for (int kt = 0; kt < 4; ++kt) {
            S8 s;
            const float* src = Wh + (size_t)j * HH + kt * 32 + quad * 8;
            #pragma unroll
            for (int e = 0; e < 8; ++e) s.u[e] = f2bf(src[e]);
            wh[nt][kt] = s.v;
        }
        #pragma unroll
        for (int c = 0; c < 3; ++c) {
            S8 s;
            #pragma unroll
            for (int e = 0; e < 8; ++e) {
                int p = c * 32 + quad * 8 + e;
                float val = 0.f;
                if (p < VV)                    val = emb[(size_t)p * HH + j];
                else if (p == 40)              val = b_h[j];
                else if (p >= 41 && p <= 48) { float t0 = emb[(size_t)(32 + p - 41) * HH + j];
                                               val = t0 - bf2f(f2bf(t0)); }
                else if (p >= 64 && p < 96)  { float t0 = emb[(size_t)(p - 64) * HH + j];
                                               val = t0 - bf2f(f2bf(t0)); }
                s.u[e] = f2bf(val);
            }
            wh[nt][4 + c] = s.v;
        }
    }
    // Wo logit frags: wave w<3 owns v-tile 16w..16w+15 (v>=40 zeroed)
    s16x8 wo[4];
    float by = 0.f;
    {
        int v = 16 * w + l16;
        bool hasv = (w < 3) && (v < VV);
        #pragma unroll
        for (int kt = 0; kt < 4; ++kt) {
            S8 s;
            #pragma unroll
            for (int e = 0; e < 8; ++e)
                s.u[e] = hasv ? f2bf(Wo[(size_t)v * HH + kt * 32 + quad * 8 + e]) : 0;
            wo[kt] = s.v;
        }
        if (hasv) by = b_y[v];
    }
    __syncthreads();

    // ---- bootstrap: A-frags (h_0), onehot frags for t=0 ----
    s16x8 af[4], oh[3];
    #pragma unroll
    for (int kt = 0; kt < 4; ++kt)
        af[kt] = *(const s16x8*)(&htile[0][l16 * HPAD + kt * 32 + quad * 8]);
    {
        int xv = xs[l16 << 10];
        #pragma unroll
        for (int c = 0; c < 3; ++c)
            oh[c] = *(const s16x8*)(&ohtab[xv * 96 + c * 32 + quad * 8]);
    }

    float hn0[4], hn1[4];
    const size_t outLV = (size_t)LL * VV;
    const int vmy = 16 * w + l16;
    const bool storev = (w < 3) && (vmy < VV);

    for (int t = 0; t < LL; ++t) {
        const int wb = (t + 1) & 1;
        // prefetch next x id (used for table reads below)
        int tn = (t + 1 < LL) ? (t + 1) : (LL - 1);
        int xvn = xs[(l16 << 10) + tn];

        // ---- recurrence: 2 n-tiles x 7-frag chains; logits[t-1] piggyback ----
        f32x4 acc0 = {0.f, 0.f, 0.f, 0.f};
        f32x4 acc1 = {0.f, 0.f, 0.f, 0.f};
        f32x4 lacc = {0.f, 0.f, 0.f, 0.f};
        #pragma unroll
        for (int f = 0; f < 7; ++f) {
            s16x8 a = (f < 4) ? af[f] : oh[f - 4];
            acc0 = MFMA(a, wh[0][f], acc0);
            acc1 = MFMA(a, wh[1][f], acc1);
        }
        #pragma unroll
        for (int kt = 0; kt < 4; ++kt) lacc = MFMA(af[kt], wo[kt], lacc);

        // ---- tanh + bf16 h write (C layout: m = quad*4+r, col = l16) ----
        unsigned short* hw = &htile[wb][0];
        #pragma unroll
        for (int r = 0; r < 4; ++r) {
            hn0[r] = fast_tanh(acc0[r]);
            hn1[r] = fast_tanh(acc1[r]);
            int m = quad * 4 + r;
            hw[m * HPAD + 32 * w + l16]      = f2bf(hn0[r]);
            hw[m * HPAD + 32 * w + 16 + l16] = f2bf(hn1[r]);
        }
        // ---- store logits row t-1 (lacc used af = h_t) ----
        if (storev && t > 0) {
            #pragma unroll
            for (int r = 0; r < 4; ++r) {
                int m = quad * 4 + r;
                out[(size_t)(b0 + m) * outLV + (size_t)(t - 1) * VV + vmy] = lacc[r] + by;
            }
        }
        // ---- next onehot frags (read-only table; safe pre-barrier) ----
        #pragma unroll
        for (int c = 0; c < 3; ++c)
            oh[c] = *(const s16x8*)(&ohtab[xvn * 96 + c * 32 + quad * 8]);

        __syncthreads();
        // ---- reload A-frags = h_{t+1} ----
        const unsigned short* hr = &htile[wb][0];
        #pragma unroll
        for (int kt = 0; kt < 4; ++kt)
            af[kt] = *(const s16x8*)(hr + l16 * HPAD + kt * 32 + quad * 8);
    }

    // ---- epilogue: logits row L-1 from final h; final hidden fp32 ----
    {
        f32x4 lacc = {0.f, 0.f, 0.f, 0.f};
        #pragma unroll
        for (int kt = 0; kt < 4; ++kt) lacc = MFMA(af[kt], wo[kt], lacc);
        if (storev) {
            #pragma unroll
            for (int r = 0; r < 4; ++r) {
                int m = quad * 4 + r;
                out[(size_t)(b0 + m) * outLV + (size_t)(LL - 1) * VV + vmy] = lacc[r] + by;
            }
        }
        float* fh = out + (size_t)BB * LL * VV;
        #pragma unroll
        for (int r = 0; r < 4; ++r) {
            int m = quad * 4 + r;
            fh[(size_t)(b0 + m) * HH + 32 * w + l16]      = hn0[r];
            fh[(size_t)(b0 + m) * HH + 32 * w + 16 + l16] = hn1[r];
        }
    }
}

extern "C" void kernel_launch(void* const* d_in, const int* in_sizes, int n_in,
                              void* d_out, int out_size, void* d_ws, size_t ws_size,
                              hipStream_t stream) {
    const int*   x      = (const int*)  d_in[0];
    const float* hidden = (const float*)d_in[1];
    const float* emb    = (const float*)d_in[2];
    const float* Wh     = (const float*)d_in[3];
    const float* Wo     = (const float*)d_in[4];
    const float* bh     = (const float*)d_in[5];
    const float* by     = (const float*)d_in[6];
    float*       out    = (float*)      d_out;

    rnn_mfma<<<dim3(BB / MROWS), dim3(256), 0, stream>>>(x, hidden, emb, Wh, Wo, bh, by, out);
}

// Round 8
// 655.418 us; speedup vs baseline: 1.2160x; 1.0221x over previous
//
#include <hip/hip_runtime.h>
#include <stdint.h>

// CharRNN via MFMA: B=256, L=1024, V=40, H=128.
// 16 blocks x 16 batch rows; per step: h_new[16,128] = tanh([h | onehot(x) | 1]
//   @ [Wh | emb^T(+residual) | b_h]^T) as 16x16x32 bf16 MFMA chains.
// R8 changes vs R7 (1416 cy/step measured):
//  - steady-loop barrier = "s_waitcnt lgkmcnt(0); s_barrier" inline asm:
//    __syncthreads() drains vmcnt(0) -> every step paid an HBM store
//    round-trip for the 12 fire-and-forget logit stores. LDS h-exchange only
//    needs lgkmcnt. (m97 barrier-drain lesson.)
//  - MFMA accumulate chains split: depth 7 -> two parallel chains (4+3) +
//    vector add; logit chain stays depth 4. Worst dependent depth now 4.
//  - xs transposed to [t][m]: old [m][t] layout put all 16 rows' bytes in one
//    bank (lane stride 1024B) -> 16-way conflict each step.

#define BB 256
#define LL 1024
#define VV 40
#define HH 128
#define MROWS 16
#define HPAD 136   // bf16 elements per h row: stride 68 words spreads quads

typedef float f32x4 __attribute__((ext_vector_type(4)));
typedef short s16x8 __attribute__((ext_vector_type(8)));

union S8 { s16x8 v; unsigned short u[8]; };

__device__ __forceinline__ unsigned short f2bf(float f) {
    unsigned int u = __float_as_uint(f);
    return (unsigned short)((u + 0x7FFFu + ((u >> 16) & 1u)) >> 16);  // RNE
}
__device__ __forceinline__ float bf2f(unsigned short h) {
    return __uint_as_float(((unsigned int)h) << 16);
}
__device__ __forceinline__ float fast_tanh(float x) {
    // tanh(x) = 1 - 2/(exp(2x)+1); overflow -> inf -> rcp -> 0 -> +1 (correct)
    float e = __expf(2.0f * x);
    float r = __builtin_amdgcn_rcpf(e + 1.0f);
    return 1.0f - 2.0f * r;
}
__device__ __forceinline__ f32x4 MFMA(s16x8 a, s16x8 b, f32x4 c) {
    return __builtin_amdgcn_mfma_f32_16x16x32_bf16(a, b, c, 0, 0, 0);
}
// Workgroup barrier WITHOUT the vmcnt(0) drain __syncthreads() would emit.
// LDS/SMEM ordering (lgkmcnt) is all the h-exchange needs; global stores are
// fire-and-forget until end of kernel.
__device__ __forceinline__ void barrier_lds() {
    asm volatile("s_waitcnt lgkmcnt(0)\n\ts_barrier" ::: "memory");
}

__global__ __launch_bounds__(256, 1) void rnn_mfma(
    const int*   __restrict__ x,       // [B,L]
    const float* __restrict__ hidden,  // [B,H]
    const float* __restrict__ emb,     // [V,H]
    const float* __restrict__ Wh,      // [H,H]
    const float* __restrict__ Wo,      // [V,H]
    const float* __restrict__ b_h,     // [H]
    const float* __restrict__ b_y,     // [V]
    float*       __restrict__ out)     // [B*L*V logits][B*H final_hidden]
{
    __shared__ unsigned char xs[LL * MROWS];                        // 16 KB [t][m]
    __shared__ alignas(16) unsigned short htile[2][MROWS * HPAD];   // 8.5 KB
    __shared__ alignas(16) unsigned short ohtab[VV * 96];           // 7.5 KB

    const int tid  = threadIdx.x;
    const int w    = tid >> 6;       // wave 0..3
    const int lane = tid & 63;
    const int quad = lane >> 4;
    const int l16  = lane & 15;
    const int b0   = blockIdx.x * MROWS;

    // ---- stage x transposed: xs[t][m] ----
    for (int i = tid; i < MROWS * LL; i += 256) {
        int m = i >> 10, t = i & (LL - 1);
        xs[t * MROWS + m] = (unsigned char)x[(size_t)(b0 + m) * LL + t];
    }
    // ---- onehot A-table: row v (96 bf16) covers k-aug positions p=0..95 ----
    for (int i = tid; i < VV * 96; i += 256) ohtab[i] = 0;
    __syncthreads();
    if (tid < VV) {
        const unsigned short one = 0x3F80;                  // bf16(1.0)
        ohtab[tid * 96 + tid] = one;                        // main onehot
        ohtab[tid * 96 + 40]  = one;                        // bias column
        int pr = (tid < 32) ? (64 + tid) : (41 + (tid - 32));
        ohtab[tid * 96 + pr]  = one;                        // residual onehot
    }
    // ---- h_init -> htile[0] (bf16) ----
    for (int i = tid; i < MROWS * HH; i += 256) {
        int m = i >> 7, k = i & (HH - 1);
        htile[0][m * HPAD + k] = f2bf(hidden[(size_t)(b0 + m) * HH + k]);
    }

    // ---- B-frags in registers ----
    // wh[nt][f]: n-tile j = 32w+16nt+l16; f<4: Wh[j][k]; f>=4: aug columns.
    s16x8 wh[2][7];
    #pragma unroll
    for (int nt = 0; nt < 2; ++nt) {
        int j = 32 * w + 16 * nt + l16;
        #pragma unroll
        for (int kt = 0; kt < 4; ++kt) {
            S8 s;
            const float* src = Wh + (size_t)j * HH + kt * 32 + quad * 8;
            #pragma unroll
            for (int e = 0; e < 8; ++e) s.u[e] = f2bf(src[e]);
            wh[nt][kt] = s.v;
        }
        #pragma unroll
        for (int c = 0; c < 3; ++c) {
            S8 s;
            #pragma unroll
            for (int e = 0; e < 8; ++e) {
                int p = c * 32 + quad * 8 + e;
                float val = 0.f;
                if (p < VV)                    val = emb[(size_t)p * HH + j];
                else if (p == 40)              val = b_h[j];
                else if (p >= 41 && p <= 48) { float t0 = emb[(size_t)(32 + p - 41) * HH + j];
                                               val = t0 - bf2f(f2bf(t0)); }
                else if (p >= 64 && p < 96)  { float t0 = emb[(size_t)(p - 64) * HH + j];
                                               val = t0 - bf2f(f2bf(t0)); }
                s.u[e] = f2bf(val);
            }
            wh[nt][4 + c] = s.v;
        }
    }
    // Wo logit frags: wave w<3 owns v-tile 16w..16w+15 (v>=40 zeroed)
    s16x8 wo[4];
    float by = 0.f;
    {
        int v = 16 * w + l16;
        bool hasv = (w < 3) && (v < VV);
        #pragma unroll
        for (int kt = 0; kt < 4; ++kt) {
            S8 s;
            #pragma unroll
            for (int e = 0; e < 8; ++e)
                s.u[e] = hasv ? f2bf(Wo[(size_t)v * HH + kt * 32 + quad * 8 + e]) : 0;
            wo[kt] = s.v;
        }
        if (hasv) by = b_y[v];
    }
    __syncthreads();

    // ---- bootstrap: A-frags (h_0), onehot frags for t=0 ----
    s16x8 af[4], oh[3];
    #pragma unroll
    for (int kt = 0; kt < 4; ++kt)
        af[kt] = *(const s16x8*)(&htile[0][l16 * HPAD + kt * 32 + quad * 8]);
    {
        int xv = xs[l16];   // t=0
        #pragma unroll
        for (int c = 0; c < 3; ++c)
            oh[c] = *(const s16x8*)(&ohtab[xv * 96 + c * 32 + quad * 8]);
    }

    float hn0[4], hn1[4];
    const size_t outLV = (size_t)LL * VV;
    const int vmy = 16 * w + l16;
    const bool storev = (w < 3) && (vmy < VV);

    for (int t = 0; t < LL; ++t) {
        const int wb = (t + 1) & 1;
        // prefetch next x id (byte read, [t][m] layout: single-cycle)
        int tn = (t + 1 < LL) ? (t + 1) : (LL - 1);
        int xvn = xs[tn * MROWS + l16];

        // ---- recurrence: two parallel chains per n-tile (depth 4 + 3) ----
        f32x4 acc0 = {0.f, 0.f, 0.f, 0.f};
        f32x4 acc1 = {0.f, 0.f, 0.f, 0.f};
        f32x4 acc0b = {0.f, 0.f, 0.f, 0.f};
        f32x4 acc1b = {0.f, 0.f, 0.f, 0.f};
        f32x4 lacc = {0.f, 0.f, 0.f, 0.f};
        #pragma unroll
        for (int f = 0; f < 4; ++f) {
            acc0 = MFMA(af[f], wh[0][f], acc0);
            acc1 = MFMA(af[f], wh[1][f], acc1);
        }
        #pragma unroll
        for (int c = 0; c < 3; ++c) {
            acc0b = MFMA(oh[c], wh[0][4 + c], acc0b);
            acc1b = MFMA(oh[c], wh[1][4 + c], acc1b);
        }
        #pragma unroll
        for (int kt = 0; kt < 4; ++kt) lacc = MFMA(af[kt], wo[kt], lacc);
        acc0 += acc0b;
        acc1 += acc1b;

        // ---- tanh + bf16 h write (C layout: m = quad*4+r, col = l16) ----
        unsigned short* hw = &htile[wb][0];
        #pragma unroll
        for (int r = 0; r < 4; ++r) {
            hn0[r] = fast_tanh(acc0[r]);
            hn1[r] = fast_tanh(acc1[r]);
            int m = quad * 4 + r;
            hw[m * HPAD + 32 * w + l16]      = f2bf(hn0[r]);
            hw[m * HPAD + 32 * w + 16 + l16] = f2bf(hn1[r]);
        }
        // ---- store logits row t-1 (lacc used af = h_t); NOT drained by the
        //      barrier below (lgkmcnt-only barrier) ----
        if (storev && t > 0) {
            #pragma unroll
            for (int r = 0; r < 4; ++r) {
                int m = quad * 4 + r;
                out[(size_t)(b0 + m) * outLV + (size_t)(t - 1) * VV + vmy] = lacc[r] + by;
            }
        }
        // ---- next onehot frags (read-only table; safe pre-barrier) ----
        #pragma unroll
        for (int c = 0; c < 3; ++c)
            oh[c] = *(const s16x8*)(&ohtab[xvn * 96 + c * 32 + quad * 8]);

        barrier_lds();   // lgkmcnt(0) + s_barrier, NO vmcnt drain
        // ---- reload A-frags = h_{t+1} ----
        const unsigned short* hr = &htile[wb][0];
        #pragma unroll
        for (int kt = 0; kt < 4; ++kt)
            af[kt] = *(const s16x8*)(hr + l16 * HPAD + kt * 32 + quad * 8);
    }

    // ---- epilogue: logits row L-1 from final h; final hidden fp32 ----
    {
        f32x4 lacc = {0.f, 0.f, 0.f, 0.f};
        #pragma unroll
        for (int kt = 0; kt < 4; ++kt) lacc = MFMA(af[kt], wo[kt], lacc);
        if (storev) {
            #pragma unroll
            for (int r = 0; r < 4; ++r) {
                int m = quad * 4 + r;
                out[(size_t)(b0 + m) * outLV + (size_t)(LL - 1) * VV + vmy] = lacc[r] + by;
            }
        }
        float* fh = out + (size_t)BB * LL * VV;
        #pragma unroll
        for (int r = 0; r < 4; ++r) {
            int m = quad * 4 + r;
            fh[(size_t)(b0 + m) * HH + 32 * w + l16]      = hn0[r];
            fh[(size_t)(b0 + m) * HH + 32 * w + 16 + l16] = hn1[r];
        }
    }
}

extern "C" void kernel_launch(void* const* d_in, const int* in_sizes, int n_in,
                              void* d_out, int out_size, void* d_ws, size_t ws_size,
                              hipStream_t stream) {
    const int*   x      = (const int*)  d_in[0];
    const float* hidden = (const float*)d_in[1];
    const float* emb    = (const float*)d_in[2];
    const float* Wh     = (const float*)d_in[3];
    const float* Wo     = (const float*)d_in[4];
    const float* bh     = (const float*)d_in[5];
    const float* by     = (const float*)d_in[6];
    float*       out    = (float*)      d_out;

    rnn_mfma<<<dim3(BB / MROWS), dim3(256), 0, stream>>>(x, hidden, emb, Wh, Wo, bh, by, out);
}